// Round 9
// baseline (278.759 us; speedup 1.0000x reference)
//
#include <hip/hip_runtime.h>

// TinyAttention on MI355X: b=4, t=2048, d=1024, single head.
// R16: repack 5 dispatches -> 4 with co-scheduled independent work.
//  D1 head : g1 (WqkT via f32-direct reg-staging, both operands row-major in
//            w_qkv) runs its 64 latency-bound blocks under the x/wqkv casts +
//            wproj transpose (12352 blocks total).
//  D2 mix2 : t1 = xbf@WqkT^T (512 blocks) + g2 W2vT = wprojT x wv (64 blocks,
//            standard bf16 staging). Same epilogue for both paths.
//  D3 mix3 : S = exp(t1@xbf^T/32) causal (544 triangular blocks) + VW = xbf@
//            W2vT^T with transposed store -> VWT (512 blocks). 1056 blocks.
//  D4 pv   : unchanged verified PV (in-loop rowsum, z-complementary pairing).
// Core everywhere: R11-verified 16x16x32 MFMA, 64B LDS rows, parity-XOR
// both-sides swizzle, conflict-free, 4 blocks/CU.

typedef __bf16 bf16x8_t __attribute__((ext_vector_type(8)));
typedef float  f32x4_t  __attribute__((ext_vector_type(4)));
typedef unsigned short u16;
typedef unsigned short u16x8_t __attribute__((ext_vector_type(8)));

struct alignas(8) u16x4 { u16 x, y, z, w; };

__device__ inline u16 f2bf(float f) {  // round-to-nearest-even
  union { float f; unsigned u; } c; c.f = f;
  unsigned r = c.u + 0x7fffu + ((c.u >> 16) & 1u);
  return (u16)(r >> 16);
}

// ===========================================================================
// D4: PV kernel — verbatim R15 gemm_bt, used only as <4,2>.
// OUTMODE 4 = PV': y = acc/rowsum + bias, f32 row-major (rowsum in-loop from E)
// GRIDMODE 2 = K<=bm0+128, z-complementary row pairing
// ===========================================================================
template<int OUTMODE, int GRIDMODE>
__global__ __launch_bounds__(256, 4)
void gemm_bt(const u16* __restrict__ A, const u16* __restrict__ B,
             const u16* __restrict__ B2,
             void* __restrict__ Cv, u16* __restrict__ C2,
             const float* __restrict__ bias,
             int K, int lda, int ldb, int ldc,
             long sA, long sB, long sC)
{
  int bn0, bm0;
  if (GRIDMODE == 2) {
    bn0 = blockIdx.x * 128;
    const int gy = (int)gridDim.y;
    const int yy = (blockIdx.z & 2) ? (int)blockIdx.y : (gy - 1 - (int)blockIdx.y);
    bm0 = yy * 128;
  } else {
    bn0 = blockIdx.x * 128;
    bm0 = blockIdx.y * 128;
  }
  const long bz = blockIdx.z;
  const u16* Ab = A + bz * sA;
  const u16* Bb = B + bz * sB;
  const int Keff = (GRIDMODE == 2) ? min(K, bm0 + 128) : K;

  __shared__ __align__(16) u16 lA[2 * 128 * 32];
  __shared__ __align__(16) u16 lB[2 * 128 * 32];

  const int tid  = threadIdx.x;
  const int lane = tid & 63;
  const int wv   = tid >> 6;
  const int wm   = (wv >> 1) << 6;
  const int wn   = (wv & 1) << 6;
  const int l15  = lane & 15;
  const int rd_off = l15 * 64 + ((((lane >> 4) ^ (l15 >> 1)) & 3) << 4);

  f32x4_t acc[4][4];
#pragma unroll
  for (int i = 0; i < 4; ++i)
#pragma unroll
    for (int j = 0; j < 4; ++j)
      acc[i][j] = (f32x4_t){0.f, 0.f, 0.f, 0.f};

  float rsacc = 0.f;

  const long ldA2 = (long)lda * 2, ldB2 = (long)ldb * 2;
  const int c_src = (tid & 3) ^ ((tid >> 3) & 3);
  const char* pA = (const char*)(Ab + (long)bm0 * lda) + (long)(tid >> 2) * ldA2 + (c_src << 4);
  const char* pB = (const char*)(Bb + (long)bn0 * ldb) + (long)(tid >> 2) * ldB2 + (c_src << 4);
  const int ldsbo = tid * 16;

  for (int k0 = 0; k0 < Keff; k0 += 64) {
    const long kb = (long)k0 * 2;
#pragma unroll
    for (int r = 0; r < 4; ++r) {
      const long go = (long)(r & 1) * 64 * ldA2 + (r >> 1) * 64;
      __builtin_amdgcn_global_load_lds(
          (const __attribute__((address_space(1))) unsigned int*)(pA + kb + go),
          (__attribute__((address_space(3))) unsigned int*)((char*)lA + ldsbo + r * 4096), 16, 0, 0);
    }
#pragma unroll
    for (int r = 0; r < 4; ++r) {
      const long go = (long)(r & 1) * 64 * ldB2 + (r >> 1) * 64;
      __builtin_amdgcn_global_load_lds(
          (const __attribute__((address_space(1))) unsigned int*)(pB + kb + go),
          (__attribute__((address_space(3))) unsigned int*)((char*)lB + ldsbo + r * 4096), 16, 0, 0);
    }
    __syncthreads();

    const char* lAb = (const char*)lA + wm * 64 + rd_off;
    const char* lBb = (const char*)lB + wn * 64 + rd_off;
#pragma unroll
    for (int s = 0; s < 2; ++s) {
      const int so = s * 8192;
      bf16x8_t b0 = *(const bf16x8_t*)(lBb + so + 0 * 1024);
      bf16x8_t b1 = *(const bf16x8_t*)(lBb + so + 1 * 1024);
      bf16x8_t b2 = *(const bf16x8_t*)(lBb + so + 2 * 1024);
      bf16x8_t b3 = *(const bf16x8_t*)(lBb + so + 3 * 1024);
#pragma unroll
      for (int mf = 0; mf < 4; ++mf) {
        bf16x8_t a = *(const bf16x8_t*)(lAb + so + mf * 1024);
        acc[mf][0] = __builtin_amdgcn_mfma_f32_16x16x32_bf16(a, b0, acc[mf][0], 0, 0, 0);
        acc[mf][1] = __builtin_amdgcn_mfma_f32_16x16x32_bf16(a, b1, acc[mf][1], 0, 0, 0);
        acc[mf][2] = __builtin_amdgcn_mfma_f32_16x16x32_bf16(a, b2, acc[mf][2], 0, 0, 0);
        acc[mf][3] = __builtin_amdgcn_mfma_f32_16x16x32_bf16(a, b3, acc[mf][3], 0, 0, 0);
      }
    }

    if (OUTMODE == 4) {
      const int rr = tid >> 1;
      const int bsel = (tid & 1) * 8192;
#pragma unroll
      for (int c = 0; c < 4; ++c) {
        const int cc = (c + (rr >> 1)) & 3;
        bf16x8_t v = *(const bf16x8_t*)((const char*)lA + bsel + rr * 64 + cc * 16);
#pragma unroll
        for (int e = 0; e < 8; ++e) rsacc += (float)v[e];
      }
    }
    __syncthreads();
  }

  const int r4 = (lane >> 4) << 2;

  if (OUTMODE == 4) {
    float* rsl = (float*)lA;
    rsl[tid] = rsacc;
    __syncthreads();
    float* rinv = (float*)lB;
    if (tid < 128) rinv[tid] = 1.0f / (rsl[2 * tid] + rsl[2 * tid + 1]);
    __syncthreads();
    float* Yf = (float*)Cv + bz * sC;
#pragma unroll
    for (int mf = 0; mf < 4; ++mf)
#pragma unroll
      for (int nf = 0; nf < 4; ++nf) {
        const int col = bn0 + wn + nf * 16 + l15;
        const float bb = bias[col];
#pragma unroll
        for (int r = 0; r < 4; ++r) {
          const int rl = wm + mf * 16 + r4 + r;
          Yf[(long)(bm0 + rl) * ldc + col] = acc[mf][nf][r] * rinv[rl] + bb;
        }
      }
    return;
  }
  (void)B2; (void)C2;
}

// ===========================================================================
// D1 head: blocks 0..63 = g1 (WqkT, f32-direct); 64..8255 x-cast;
//          8256..11327 wqkv-cast; 11328..12351 wproj transpose.
// g1: WqkT[f][e] = sum_a wqkv[f][1024+a] * wqkv[e][a]  (both row-major f32)
// ===========================================================================
__global__ __launch_bounds__(256, 4)
void head(const float* __restrict__ x, const float* __restrict__ wqkv,
          const float* __restrict__ wproj,
          u16* __restrict__ xbf, u16* __restrict__ wfull,
          u16* __restrict__ wprojT, u16* __restrict__ WqkT)
{
  __shared__ __align__(16) u16 lA[2 * 128 * 32];
  __shared__ __align__(16) u16 lB[2 * 128 * 32];
  const int bid = blockIdx.x;
  const int tid = threadIdx.x;

  if (bid >= 64) {
    const int cb = bid - 64;
    if (cb < 8192) {                       // x -> bf16
      const int i = cb * 256 + tid;
      float4 v = ((const float4*)x)[i];
      u16x4 o = {f2bf(v.x), f2bf(v.y), f2bf(v.z), f2bf(v.w)};
      ((u16x4*)xbf)[i] = o;
      return;
    }
    if (cb < 11264) {                      // wqkv -> bf16
      const int i = (cb - 8192) * 256 + tid;
      float4 v = ((const float4*)wqkv)[i];
      u16x4 o = {f2bf(v.x), f2bf(v.y), f2bf(v.z), f2bf(v.w)};
      ((u16x4*)wfull)[i] = o;
      return;
    }
    const int tb = cb - 11264;             // wproj [1024][1024] transpose
    const int c0 = (tb & 31) * 32;
    const int r0 = (tb >> 5) * 32;
    __shared__ float t[32][33];
    const int tx = tid & 31, ty = tid >> 5;
#pragma unroll
    for (int i = 0; i < 32; i += 8)
      t[ty + i][tx] = wproj[(long)(r0 + ty + i) * 1024 + (c0 + tx)];
    __syncthreads();
#pragma unroll
    for (int i = 0; i < 32; i += 8)
      wprojT[(long)(c0 + ty + i) * 1024 + (r0 + tx)] = f2bf(t[tx][ty + i]);
    return;
  }

  // --- g1: f32-direct reg-staging GEMM, K=1024 ---
  const int bm0 = (bid >> 3) * 128, bn0 = (bid & 7) * 128;
  const int lane = tid & 63;
  const int wv   = tid >> 6;
  const int wm   = (wv >> 1) << 6;
  const int wn   = (wv & 1) << 6;
  const int l15  = lane & 15;
  const int rd_off = l15 * 64 + ((((lane >> 4) ^ (l15 >> 1)) & 3) << 4);
  const int c_src = (tid & 3) ^ ((tid >> 3) & 3);
  const int rowA = tid >> 2;             // 0..63

  f32x4_t acc[4][4];
#pragma unroll
  for (int i = 0; i < 4; ++i)
#pragma unroll
    for (int j = 0; j < 4; ++j)
      acc[i][j] = (f32x4_t){0.f, 0.f, 0.f, 0.f};

  for (int k0 = 0; k0 < 1024; k0 += 64) {
#pragma unroll
    for (int r = 0; r < 4; ++r) {
      const int row = rowA + (r & 1) * 64;
      const int klog = k0 + (r >> 1) * 32 + c_src * 8;
      // A-row f = bm0+row: wqkv[f][1024+klog..+8]  (Wk part)
      const float* pa = wqkv + (long)(bm0 + row) * 3072 + 1024 + klog;
      float4 a0 = *(const float4*)pa, a1 = *(const float4*)(pa + 4);
      u16x8_t av = {f2bf(a0.x), f2bf(a0.y), f2bf(a0.z), f2bf(a0.w),
                    f2bf(a1.x), f2bf(a1.y), f2bf(a1.z), f2bf(a1.w)};
      *(u16x8_t*)((char*)lA + tid * 16 + r * 4096) = av;
      // B-row e = bn0+row: wqkv[e][klog..+8]  (Wq part)
      const float* pb = wqkv + (long)(bn0 + row) * 3072 + klog;
      float4 b0v = *(const float4*)pb, b1v = *(const float4*)(pb + 4);
      u16x8_t bv = {f2bf(b0v.x), f2bf(b0v.y), f2bf(b0v.z), f2bf(b0v.w),
                    f2bf(b1v.x), f2bf(b1v.y), f2bf(b1v.z), f2bf(b1v.w)};
      *(u16x8_t*)((char*)lB + tid * 16 + r * 4096) = bv;
    }
    __syncthreads();

    const char* lAb = (const char*)lA + wm * 64 + rd_off;
    const char* lBb = (const char*)lB + wn * 64 + rd_off;
#pragma unroll
    for (int s = 0; s < 2; ++s) {
      const int so = s * 8192;
      bf16x8_t b0 = *(const bf16x8_t*)(lBb + so + 0 * 1024);
      bf16x8_t b1 = *(const bf16x8_t*)(lBb + so + 1 * 1024);
      bf16x8_t b2 = *(const bf16x8_t*)(lBb + so + 2 * 1024);
      bf16x8_t b3 = *(const bf16x8_t*)(lBb + so + 3 * 1024);
#pragma unroll
      for (int mf = 0; mf < 4; ++mf) {
        bf16x8_t a = *(const bf16x8_t*)(lAb + so + mf * 1024);
        acc[mf][0] = __builtin_amdgcn_mfma_f32_16x16x32_bf16(a, b0, acc[mf][0], 0, 0, 0);
        acc[mf][1] = __builtin_amdgcn_mfma_f32_16x16x32_bf16(a, b1, acc[mf][1], 0, 0, 0);
        acc[mf][2] = __builtin_amdgcn_mfma_f32_16x16x32_bf16(a, b2, acc[mf][2], 0, 0, 0);
        acc[mf][3] = __builtin_amdgcn_mfma_f32_16x16x32_bf16(a, b3, acc[mf][3], 0, 0, 0);
      }
    }
    __syncthreads();
  }

  const int r4 = (lane >> 4) << 2;
#pragma unroll
  for (int mf = 0; mf < 4; ++mf)
#pragma unroll
    for (int nf = 0; nf < 4; ++nf) {
      const int col = bn0 + wn + nf * 16 + l15;
#pragma unroll
      for (int r = 0; r < 4; ++r)
        WqkT[(long)(bm0 + wm + mf * 16 + r4 + r) * 1024 + col] = f2bf(acc[mf][nf][r]);
    }
}

// ===========================================================================
// D2 mix2: grid (8, 72). y<64: t1 = xbf@WqkT^T; y>=64: g2 W2vT = wprojT x wv.
// Both: bf16 row-major out, ldc 1024, K=1024, standard staging.
// ===========================================================================
__global__ __launch_bounds__(256, 4)
void mix2(const u16* __restrict__ xbf, const u16* __restrict__ WqkT,
          const u16* __restrict__ wprojT, const u16* __restrict__ wfull,
          u16* __restrict__ t1, u16* __restrict__ W2vT)
{
  const int xb = blockIdx.x, yb = blockIdx.y;
  const bool g2 = yb >= 64;
  const int bm0 = (g2 ? (yb - 64) : yb) * 128;
  const int bn0 = xb * 128;
  const u16* Ab = g2 ? wprojT : xbf;
  const u16* Bb = g2 ? (wfull + 2048) : WqkT;
  const int ldb = g2 ? 3072 : 1024;
  u16* C = g2 ? W2vT : t1;

  __shared__ __align__(16) u16 lA[2 * 128 * 32];
  __shared__ __align__(16) u16 lB[2 * 128 * 32];

  const int tid  = threadIdx.x;
  const int lane = tid & 63;
  const int wv   = tid >> 6;
  const int wm   = (wv >> 1) << 6;
  const int wn   = (wv & 1) << 6;
  const int l15  = lane & 15;
  const int rd_off = l15 * 64 + ((((lane >> 4) ^ (l15 >> 1)) & 3) << 4);

  f32x4_t acc[4][4];
#pragma unroll
  for (int i = 0; i < 4; ++i)
#pragma unroll
    for (int j = 0; j < 4; ++j)
      acc[i][j] = (f32x4_t){0.f, 0.f, 0.f, 0.f};

  const long ldA2 = 1024 * 2, ldB2 = (long)ldb * 2;
  const int c_src = (tid & 3) ^ ((tid >> 3) & 3);
  const char* pA = (const char*)(Ab + (long)bm0 * 1024) + (long)(tid >> 2) * ldA2 + (c_src << 4);
  const char* pB = (const char*)(Bb + (long)bn0 * ldb) + (long)(tid >> 2) * ldB2 + (c_src << 4);
  const int ldsbo = tid * 16;

  for (int k0 = 0; k0 < 1024; k0 += 64) {
    const long kb = (long)k0 * 2;
#pragma unroll
    for (int r = 0; r < 4; ++r) {
      const long go = (long)(r & 1) * 64 * ldA2 + (r >> 1) * 64;
      __builtin_amdgcn_global_load_lds(
          (const __attribute__((address_space(1))) unsigned int*)(pA + kb + go),
          (__attribute__((address_space(3))) unsigned int*)((char*)lA + ldsbo + r * 4096), 16, 0, 0);
    }
#pragma unroll
    for (int r = 0; r < 4; ++r) {
      const long go = (long)(r & 1) * 64 * ldB2 + (r >> 1) * 64;
      __builtin_amdgcn_global_load_lds(
          (const __attribute__((address_space(1))) unsigned int*)(pB + kb + go),
          (__attribute__((address_space(3))) unsigned int*)((char*)lB + ldsbo + r * 4096), 16, 0, 0);
    }
    __syncthreads();

    const char* lAb = (const char*)lA + wm * 64 + rd_off;
    const char* lBb = (const char*)lB + wn * 64 + rd_off;
#pragma unroll
    for (int s = 0; s < 2; ++s) {
      const int so = s * 8192;
      bf16x8_t b0 = *(const bf16x8_t*)(lBb + so + 0 * 1024);
      bf16x8_t b1 = *(const bf16x8_t*)(lBb + so + 1 * 1024);
      bf16x8_t b2 = *(const bf16x8_t*)(lBb + so + 2 * 1024);
      bf16x8_t b3 = *(const bf16x8_t*)(lBb + so + 3 * 1024);
#pragma unroll
      for (int mf = 0; mf < 4; ++mf) {
        bf16x8_t a = *(const bf16x8_t*)(lAb + so + mf * 1024);
        acc[mf][0] = __builtin_amdgcn_mfma_f32_16x16x32_bf16(a, b0, acc[mf][0], 0, 0, 0);
        acc[mf][1] = __builtin_amdgcn_mfma_f32_16x16x32_bf16(a, b1, acc[mf][1], 0, 0, 0);
        acc[mf][2] = __builtin_amdgcn_mfma_f32_16x16x32_bf16(a, b2, acc[mf][2], 0, 0, 0);
        acc[mf][3] = __builtin_amdgcn_mfma_f32_16x16x32_bf16(a, b3, acc[mf][3], 0, 0, 0);
      }
    }
    __syncthreads();
  }

  const int r4 = (lane >> 4) << 2;
#pragma unroll
  for (int mf = 0; mf < 4; ++mf)
#pragma unroll
    for (int nf = 0; nf < 4; ++nf) {
      const int col = bn0 + wn + nf * 16 + l15;
#pragma unroll
      for (int r = 0; r < 4; ++r)
        C[(long)(bm0 + wm + mf * 16 + r4 + r) * 1024 + col] = f2bf(acc[mf][nf][r]);
    }
}

// ===========================================================================
// D3 mix3: 1D grid, 1056 blocks.
//  bid<544 : S = exp(t1@xbf^T/32), causal, triangular (z = bid/136)
//  bid>=544: VW = xbf@W2vT^T with transposed store -> VWT[b][o][s]
// ===========================================================================
__global__ __launch_bounds__(256, 4)
void mix3(const u16* __restrict__ t1, const u16* __restrict__ xbf,
          const u16* __restrict__ W2vT, u16* __restrict__ E,
          u16* __restrict__ VWT)
{
  const int bid = blockIdx.x;
  const bool isS = bid < 544;
  int bm0, bn0;
  long z = 0;
  const u16 *Ab, *Bb;
  if (isS) {
    z = bid / 136;
    const int x = bid - (int)z * 136;
    int r = (int)((sqrtf(8.f * x + 1.f) - 1.f) * 0.5f);
    while ((r + 1) * (r + 2) / 2 <= x) ++r;
    while (r * (r + 1) / 2 > x) --r;
    bm0 = r * 128;
    bn0 = (x - r * (r + 1) / 2) * 128;
    Ab = t1 + z * (2048l * 1024);
    Bb = xbf + z * (2048l * 1024);
  } else {
    const int i = bid - 544;
    bm0 = (i >> 3) * 128;                 // flattened 8192 rows
    bn0 = (i & 7) * 128;                  // VW out col
    Ab = xbf;
    Bb = W2vT;
  }

  __shared__ __align__(16) u16 lA[2 * 128 * 32];
  __shared__ __align__(16) u16 lB[2 * 128 * 32];

  const int tid  = threadIdx.x;
  const int lane = tid & 63;
  const int wv   = tid >> 6;
  const int wm   = (wv >> 1) << 6;
  const int wn   = (wv & 1) << 6;
  const int l15  = lane & 15;
  const int rd_off = l15 * 64 + ((((lane >> 4) ^ (l15 >> 1)) & 3) << 4);

  f32x4_t acc[4][4];
#pragma unroll
  for (int i = 0; i < 4; ++i)
#pragma unroll
    for (int j = 0; j < 4; ++j)
      acc[i][j] = (f32x4_t){0.f, 0.f, 0.f, 0.f};

  const long ld2 = 1024 * 2;
  const int c_src = (tid & 3) ^ ((tid >> 3) & 3);
  const char* pA = (const char*)(Ab + (long)bm0 * 1024) + (long)(tid >> 2) * ld2 + (c_src << 4);
  const char* pB = (const char*)(Bb + (long)bn0 * 1024) + (long)(tid >> 2) * ld2 + (c_src << 4);
  const int ldsbo = tid * 16;

  for (int k0 = 0; k0 < 1024; k0 += 64) {
    const long kb = (long)k0 * 2;
#pragma unroll
    for (int r = 0; r < 4; ++r) {
      const long go = (long)(r & 1) * 64 * ld2 + (r >> 1) * 64;
      __builtin_amdgcn_global_load_lds(
          (const __attribute__((address_space(1))) unsigned int*)(pA + kb + go),
          (__attribute__((address_space(3))) unsigned int*)((char*)lA + ldsbo + r * 4096), 16, 0, 0);
    }
#pragma unroll
    for (int r = 0; r < 4; ++r) {
      const long go = (long)(r & 1) * 64 * ld2 + (r >> 1) * 64;
      __builtin_amdgcn_global_load_lds(
          (const __attribute__((address_space(1))) unsigned int*)(pB + kb + go),
          (__attribute__((address_space(3))) unsigned int*)((char*)lB + ldsbo + r * 4096), 16, 0, 0);
    }
    __syncthreads();

    const char* lAb = (const char*)lA + wm * 64 + rd_off;
    const char* lBb = (const char*)lB + wn * 64 + rd_off;
#pragma unroll
    for (int s = 0; s < 2; ++s) {
      const int so = s * 8192;
      bf16x8_t b0 = *(const bf16x8_t*)(lBb + so + 0 * 1024);
      bf16x8_t b1 = *(const bf16x8_t*)(lBb + so + 1 * 1024);
      bf16x8_t b2 = *(const bf16x8_t*)(lBb + so + 2 * 1024);
      bf16x8_t b3 = *(const bf16x8_t*)(lBb + so + 3 * 1024);
#pragma unroll
      for (int mf = 0; mf < 4; ++mf) {
        bf16x8_t a = *(const bf16x8_t*)(lAb + so + mf * 1024);
        acc[mf][0] = __builtin_amdgcn_mfma_f32_16x16x32_bf16(a, b0, acc[mf][0], 0, 0, 0);
        acc[mf][1] = __builtin_amdgcn_mfma_f32_16x16x32_bf16(a, b1, acc[mf][1], 0, 0, 0);
        acc[mf][2] = __builtin_amdgcn_mfma_f32_16x16x32_bf16(a, b2, acc[mf][2], 0, 0, 0);
        acc[mf][3] = __builtin_amdgcn_mfma_f32_16x16x32_bf16(a, b3, acc[mf][3], 0, 0, 0);
      }
    }
    __syncthreads();
  }

  const int r4 = (lane >> 4) << 2;

  if (isS) {
    const float scale = 0.03125f;
    const bool diag = (bm0 == bn0);
    u16* Cb16 = E + z * (2048l * 2048);
#pragma unroll
    for (int mf = 0; mf < 4; ++mf)
#pragma unroll
      for (int r = 0; r < 4; ++r) {
        const int grow = bm0 + wm + mf * 16 + r4 + r;
#pragma unroll
        for (int nf = 0; nf < 4; ++nf) {
          const int col = bn0 + wn + nf * 16 + l15;
          float e = (diag && col > grow) ? 0.f : __expf(acc[mf][nf][r] * scale);
          Cb16[(long)grow * 2048 + col] = f2bf(e);
        }
      }
    return;
  }

  // VW transposed store: VWT[b][o][s]
#pragma unroll
  for (int mf = 0; mf < 4; ++mf) {
    const int s0 = bm0 + wm + mf * 16 + r4;
    const int b_ = s0 >> 11;
    const int s_ = s0 & 2047;
#pragma unroll
    for (int nf = 0; nf < 4; ++nf) {
      const int ocol = bn0 + wn + nf * 16 + l15;
      u16x4 o = {f2bf(acc[mf][nf][0]), f2bf(acc[mf][nf][1]),
                 f2bf(acc[mf][nf][2]), f2bf(acc[mf][nf][3])};
      *(u16x4*)&VWT[(((long)b_ * 1024 + ocol) << 11) + s_] = o;
    }
  }
}

// ---------------------------------------------------------------------------
extern "C" void kernel_launch(void* const* d_in, const int* in_sizes, int n_in,
                              void* d_out, int out_size, void* d_ws, size_t ws_size,
                              hipStream_t stream) {
  (void)in_sizes; (void)n_in; (void)out_size; (void)ws_size;
  const float* x      = (const float*)d_in[0];
  const float* w_qkv  = (const float*)d_in[1];
  const float* w_proj = (const float*)d_in[2];
  const float* b_proj = (const float*)d_in[3];
  float* y = (float*)d_out;
  char*  ws = (char*)d_ws;

  // workspace layout
  u16* xbf    = (u16*)(ws);                  // 16 MB
  u16* t1     = (u16*)(ws + (16l << 20));    // 16 MB  [8192,1024] x@Wqk
  u16* WqkT   = (u16*)(ws + (32l << 20));    //  2 MB
  u16* W2vT   = (u16*)(ws + (34l << 20));    //  2 MB
  u16* wprojT = (u16*)(ws + (36l << 20));    //  2 MB
  u16* wfull  = (u16*)(ws + (38l << 20));    //  6 MB  [1024,3072] w_qkv bf16
  u16* VWT    = (u16*)(ws + (44l << 20));    // 16 MB  [4][1024][2048]
  u16* E      = (u16*)(ws + (60l << 20));    // 32 MB  [4][2048][2048]

  // D1: g1 (WqkT f32-direct) + x-cast + wqkv-cast + wproj transpose
  head<<<12352, 256, 0, stream>>>(x, w_qkv, w_proj, xbf, wfull, wprojT, WqkT);
  // D2: t1 = xbf@WqkT^T (512 blocks) + g2 W2vT (64 blocks)
  mix2<<<dim3(8, 72), 256, 0, stream>>>(xbf, WqkT, wprojT, wfull, t1, W2vT);
  // D3: S/E (544 triangular) + VW->VWT (512)
  mix3<<<1056, 256, 0, stream>>>(t1, xbf, W2vT, E, VWT);
  // D4: y = (E @ VW)/rowsum + bias, f32 out
  gemm_bt<4, 2><<<dim3(8, 16, 4), 256, 0, stream>>>(
      E, VWT, nullptr, y, nullptr, b_proj, 2048, 2048, 2048, 1024,
      (long)2048 * 2048, (long)1024 * 2048, (long)2048 * 1024);
}

// Round 10
// 235.628 us; speedup vs baseline: 1.1830x; 1.1830x over previous
//
#include <hip/hip_runtime.h>

// TinyAttention on MI355X: b=4, t=2048, d=1024, single head.
// R17: R15 structure restored verbatim (best verified, 238.3us; R16's merges
// regressed: g1-under-casts starved at 1TB/s, S+VW co-schedule thrashed L2
// FETCH 164MB). One change: PV rebuilt as pv64 — 64-row x 128-col tiles,
// grid (8,32,4) = 1024 blocks = 4/CU (PV was the only dispatch running the
// core at 2/CU: 1.3us/iter vs 0.74 at 4/CU). Keff = bm0+64 (tighter causal),
// A-staging 2 shots, 16 MFMA/iter, LDS 24KB, z-complementary pairing kept,
// in-loop rowsum at 4 threads/row. Core: R11-verified 16x16x32 MFMA, 64B LDS
// rows, parity-XOR both-sides swizzle, conflict-free.

typedef __bf16 bf16x8_t __attribute__((ext_vector_type(8)));
typedef float  f32x4_t  __attribute__((ext_vector_type(4)));
typedef unsigned short u16;

struct alignas(8) u16x4 { u16 x, y, z, w; };

__device__ inline u16 f2bf(float f) {  // round-to-nearest-even
  union { float f; unsigned u; } c; c.f = f;
  unsigned r = c.u + 0x7fffu + ((c.u >> 16) & 1u);
  return (u16)(r >> 16);
}

// OUTMODE: 2 = QKV': split N: bn0<1024 -> t1 bf16 row-major; bn0>=1024 -> VW^T
//              col-major transposed store (B-operand switches to B2),
//          3 = S: E=exp(scale*acc) bf16 + causal mask (no rowsums)
// GRIDMODE: 0 = normal, 1 = compact lower-triangular
template<int OUTMODE, int GRIDMODE>
__global__ __launch_bounds__(256, 4)
void gemm_bt(const u16* __restrict__ A, const u16* __restrict__ B,
             const u16* __restrict__ B2,
             void* __restrict__ Cv, u16* __restrict__ C2,
             const float* __restrict__ bias,
             int K, int lda, int ldb, int ldc,
             long sA, long sB, long sC)
{
  int bn0, bm0;
  if (GRIDMODE == 1) {
    const int x = blockIdx.x;                       // 0..135
    int r = (int)((sqrtf(8.f * x + 1.f) - 1.f) * 0.5f);
    while ((r + 1) * (r + 2) / 2 <= x) ++r;
    while (r * (r + 1) / 2 > x) --r;
    bm0 = r * 128;
    bn0 = (x - r * (r + 1) / 2) * 128;
  } else {
    bn0 = blockIdx.x * 128;
    bm0 = blockIdx.y * 128;
  }
  const long bz = blockIdx.z;
  const u16* Ab = A + bz * sA;
  const u16* Bb = ((OUTMODE == 2 && bn0 >= 1024) ? B2 : B) + bz * sB;
  const int effbn = (OUTMODE == 2) ? (bn0 & 1023) : bn0;
  const int Keff = K;

  __shared__ __align__(16) u16 lA[2 * 128 * 32];
  __shared__ __align__(16) u16 lB[2 * 128 * 32];

  const int tid  = threadIdx.x;
  const int lane = tid & 63;
  const int wv   = tid >> 6;
  const int wm   = (wv >> 1) << 6;
  const int wn   = (wv & 1) << 6;
  const int l15  = lane & 15;
  const int rd_off = l15 * 64 + ((((lane >> 4) ^ (l15 >> 1)) & 3) << 4);

  f32x4_t acc[4][4];
#pragma unroll
  for (int i = 0; i < 4; ++i)
#pragma unroll
    for (int j = 0; j < 4; ++j)
      acc[i][j] = (f32x4_t){0.f, 0.f, 0.f, 0.f};

  const long ldA2 = (long)lda * 2, ldB2 = (long)ldb * 2;
  const int c_src = (tid & 3) ^ ((tid >> 3) & 3);
  const char* pA = (const char*)(Ab + (long)bm0 * lda) + (long)(tid >> 2) * ldA2 + (c_src << 4);
  const char* pB = (const char*)(Bb + (long)effbn * ldb) + (long)(tid >> 2) * ldB2 + (c_src << 4);
  const int ldsbo = tid * 16;

  for (int k0 = 0; k0 < Keff; k0 += 64) {
    const long kb = (long)k0 * 2;
#pragma unroll
    for (int r = 0; r < 4; ++r) {
      const long go = (long)(r & 1) * 64 * ldA2 + (r >> 1) * 64;
      __builtin_amdgcn_global_load_lds(
          (const __attribute__((address_space(1))) unsigned int*)(pA + kb + go),
          (__attribute__((address_space(3))) unsigned int*)((char*)lA + ldsbo + r * 4096), 16, 0, 0);
    }
#pragma unroll
    for (int r = 0; r < 4; ++r) {
      const long go = (long)(r & 1) * 64 * ldB2 + (r >> 1) * 64;
      __builtin_amdgcn_global_load_lds(
          (const __attribute__((address_space(1))) unsigned int*)(pB + kb + go),
          (__attribute__((address_space(3))) unsigned int*)((char*)lB + ldsbo + r * 4096), 16, 0, 0);
    }
    __syncthreads();

    const char* lAb = (const char*)lA + wm * 64 + rd_off;
    const char* lBb = (const char*)lB + wn * 64 + rd_off;
#pragma unroll
    for (int s = 0; s < 2; ++s) {
      const int so = s * 8192;
      bf16x8_t b0 = *(const bf16x8_t*)(lBb + so + 0 * 1024);
      bf16x8_t b1 = *(const bf16x8_t*)(lBb + so + 1 * 1024);
      bf16x8_t b2 = *(const bf16x8_t*)(lBb + so + 2 * 1024);
      bf16x8_t b3 = *(const bf16x8_t*)(lBb + so + 3 * 1024);
#pragma unroll
      for (int mf = 0; mf < 4; ++mf) {
        bf16x8_t a = *(const bf16x8_t*)(lAb + so + mf * 1024);
        acc[mf][0] = __builtin_amdgcn_mfma_f32_16x16x32_bf16(a, b0, acc[mf][0], 0, 0, 0);
        acc[mf][1] = __builtin_amdgcn_mfma_f32_16x16x32_bf16(a, b1, acc[mf][1], 0, 0, 0);
        acc[mf][2] = __builtin_amdgcn_mfma_f32_16x16x32_bf16(a, b2, acc[mf][2], 0, 0, 0);
        acc[mf][3] = __builtin_amdgcn_mfma_f32_16x16x32_bf16(a, b3, acc[mf][3], 0, 0, 0);
      }
    }
    __syncthreads();
  }

  // epilogue: 16x16 D layout col=lane&15, row=(lane>>4)*4+reg
  const int r4 = (lane >> 4) << 2;

  if (OUTMODE == 2) {
    if (bn0 >= 1024) {
      // VW columns: write VWT[batch][o][s] (ld 2048), u16x4 over 4 consecutive s
#pragma unroll
      for (int mf = 0; mf < 4; ++mf) {
        const int s0 = bm0 + wm + mf * 16 + r4;
        const int b_ = s0 >> 11;
        const int s_ = s0 & 2047;
#pragma unroll
        for (int nf = 0; nf < 4; ++nf) {
          const int ocol = bn0 - 1024 + wn + nf * 16 + l15;
          u16x4 o = {f2bf(acc[mf][nf][0]), f2bf(acc[mf][nf][1]),
                     f2bf(acc[mf][nf][2]), f2bf(acc[mf][nf][3])};
          *(u16x4*)&C2[(((long)b_ * 1024 + ocol) << 11) + s_] = o;
        }
      }
    } else {
      u16* Cb16 = (u16*)Cv;
#pragma unroll
      for (int mf = 0; mf < 4; ++mf)
#pragma unroll
        for (int nf = 0; nf < 4; ++nf) {
          const int col = bn0 + wn + nf * 16 + l15;
#pragma unroll
          for (int r = 0; r < 4; ++r)
            Cb16[(long)(bm0 + wm + mf * 16 + r4 + r) * ldc + col] = f2bf(acc[mf][nf][r]);
        }
    }
    return;
  }

  if (OUTMODE == 3) {
    const float scale = 0.03125f;
    const bool diag = (bm0 == bn0);
    u16* Cb16 = (u16*)Cv + bz * sC;
#pragma unroll
    for (int mf = 0; mf < 4; ++mf)
#pragma unroll
      for (int r = 0; r < 4; ++r) {
        const int grow = bm0 + wm + mf * 16 + r4 + r;
#pragma unroll
        for (int nf = 0; nf < 4; ++nf) {
          const int col = bn0 + wn + nf * 16 + l15;
          float e = (diag && col > grow) ? 0.f : __expf(acc[mf][nf][r] * scale);
          Cb16[(long)grow * ldc + col] = f2bf(e);
        }
      }
    return;
  }
}

// ===========================================================================
// pv64: y = (E @ VW)/rowsum(E) + bias, f32 out. 64-row x 128-col tiles,
// grid (8, 32, 4) = 1024 blocks = 4/CU. Keff = bm0+64 (causal-exact).
// z-complementary pairing: z<2 -> rb=31-y (longest first), z>=2 -> rb=y.
// In-loop rowsum: 4 threads/row over the staged E tile.
// ===========================================================================
__global__ __launch_bounds__(256, 4)
void pv64(const u16* __restrict__ E, const u16* __restrict__ VWT,
          float* __restrict__ Y, const float* __restrict__ bias)
{
  const int bn0 = blockIdx.x * 128;
  const int yy  = (blockIdx.z & 2) ? (int)blockIdx.y : (31 - (int)blockIdx.y);
  const int bm0 = yy * 64;
  const long bz = blockIdx.z;
  const u16* Ab = E + bz * (2048l * 2048);
  const u16* Bb = VWT + bz * (1024l * 2048);
  const int Keff = bm0 + 64;

  // lA: [2 ksh][64 rows][32 k] = 8 KB; lB: [2 ksh][128 rows][32 k] = 16 KB
  __shared__ __align__(16) u16 lA[2 * 64 * 32];
  __shared__ __align__(16) u16 lB[2 * 128 * 32];

  const int tid  = threadIdx.x;
  const int lane = tid & 63;
  const int wv   = tid >> 6;
  const int wcol = wv * 32;            // wave covers 32 output cols
  const int l15  = lane & 15;
  const int rd_off = l15 * 64 + ((((lane >> 4) ^ (l15 >> 1)) & 3) << 4);

  f32x4_t acc[4][2];
#pragma unroll
  for (int i = 0; i < 4; ++i)
#pragma unroll
    for (int j = 0; j < 2; ++j)
      acc[i][j] = (f32x4_t){0.f, 0.f, 0.f, 0.f};

  float rsacc = 0.f;   // partial rowsum: row tid>>2, ksh tid&1, half (tid>>1)&1

  const long ld2 = 2048 * 2;
  const int c_src = (tid & 3) ^ ((tid >> 3) & 3);
  const char* pA = (const char*)(Ab + (long)bm0 * 2048) + (long)(tid >> 2) * ld2 + (c_src << 4);
  const char* pB = (const char*)(Bb + (long)bn0 * 2048) + (long)(tid >> 2) * ld2 + (c_src << 4);
  const int ldsbo = tid * 16;

  // rowsum read offsets (constant per thread)
  const int rs_rr  = tid >> 2;
  const int rs_off = ((tid & 1) << 12) + rs_rr * 64 + (((tid >> 1) & 1) << 6); // ksh*4096 + row*64 + half*64? no: half*32B
  // half selects chunks {0,1} or {2,3}: byte offset half*32
  const int rs_byte = ((tid & 1) << 12) + rs_rr * 64 + (((tid >> 1) & 1) << 5);

  for (int k0 = 0; k0 < Keff; k0 += 64) {
    const long kb = (long)k0 * 2;
    // A: 64 rows, 2 shots (ksh 0/1)
#pragma unroll
    for (int r = 0; r < 2; ++r)
      __builtin_amdgcn_global_load_lds(
          (const __attribute__((address_space(1))) unsigned int*)(pA + kb + r * 64),
          (__attribute__((address_space(3))) unsigned int*)((char*)lA + ldsbo + r * 4096), 16, 0, 0);
    // B: 128 rows, 4 shots
#pragma unroll
    for (int r = 0; r < 4; ++r) {
      const long go = (long)(r & 1) * 64 * ld2 + (r >> 1) * 64;
      __builtin_amdgcn_global_load_lds(
          (const __attribute__((address_space(1))) unsigned int*)(pB + kb + go),
          (__attribute__((address_space(3))) unsigned int*)((char*)lB + ldsbo + r * 4096), 16, 0, 0);
    }
    __syncthreads();

    const char* lAb = (const char*)lA + rd_off;
    const char* lBb = (const char*)lB + wcol * 64 + rd_off;
#pragma unroll
    for (int s = 0; s < 2; ++s) {
      const int soA = s * 4096, soB = s * 8192;
      bf16x8_t b0 = *(const bf16x8_t*)(lBb + soB + 0 * 1024);
      bf16x8_t b1 = *(const bf16x8_t*)(lBb + soB + 1 * 1024);
#pragma unroll
      for (int mf = 0; mf < 4; ++mf) {
        bf16x8_t a = *(const bf16x8_t*)(lAb + soA + mf * 1024);
        acc[mf][0] = __builtin_amdgcn_mfma_f32_16x16x32_bf16(a, b0, acc[mf][0], 0, 0, 0);
        acc[mf][1] = __builtin_amdgcn_mfma_f32_16x16x32_bf16(a, b1, acc[mf][1], 0, 0, 0);
      }
    }

    // rowsum of the staged E tile: 4 threads/row, 2 x bf16x8 each.
    // Sum is chunk-permutation-invariant -> swizzled layout irrelevant.
    {
      bf16x8_t v0 = *(const bf16x8_t*)((const char*)lA + rs_byte);
      bf16x8_t v1 = *(const bf16x8_t*)((const char*)lA + rs_byte + 16);
#pragma unroll
      for (int e = 0; e < 8; ++e) rsacc += (float)v0[e] + (float)v1[e];
    }
    __syncthreads();
  }

  // combine 4 partials/row, invert once per row
  float* rsl = (float*)lA;
  rsl[tid] = rsacc;
  __syncthreads();
  float* rinv = (float*)lB;
  if (tid < 64)
    rinv[tid] = 1.0f / (rsl[4 * tid] + rsl[4 * tid + 1] + rsl[4 * tid + 2] + rsl[4 * tid + 3]);
  __syncthreads();

  const int r4 = (lane >> 4) << 2;
  float* Yb = Y + bz * (2048l * 1024);
#pragma unroll
  for (int mf = 0; mf < 4; ++mf)
#pragma unroll
    for (int nf = 0; nf < 2; ++nf) {
      const int col = bn0 + wcol + nf * 16 + l15;
      const float bb = bias[col];
#pragma unroll
      for (int r = 0; r < 4; ++r) {
        const int rl = mf * 16 + r4 + r;
        Yb[(long)(bm0 + rl) * 1024 + col] = acc[mf][nf][r] * rinv[rl] + bb;
      }
    }
  (void)rs_off;
}

// ---------------------------------------------------------------------------
// Weight-weight products, both in one dispatch (grid 8 x 16 = 128 blocks):
//  y<8 : WqkT[f][e] = sum_a wk[f,a]*wq[e,a]   (A=wfull+1024, B=wfull, ld 3072)
//  y>=8: W2vT[o][d] = sum_e wprojT[o,e]*wv[d,e] (A=wprojT ld 1024, B=wfull+2048)
__global__ __launch_bounds__(256, 4)
void gemm_w(const u16* __restrict__ wfull, const u16* __restrict__ wprojT,
            u16* __restrict__ WqkT, u16* __restrict__ W2vT)
{
  const bool g2 = blockIdx.y >= 8;
  const int bm0 = ((int)blockIdx.y & 7) * 128;
  const int bn0 = (int)blockIdx.x * 128;
  const u16* A = g2 ? wprojT : (wfull + 1024);
  const u16* B = g2 ? (wfull + 2048) : wfull;
  const int lda = g2 ? 1024 : 3072;
  const int ldb = 3072;
  u16* C = g2 ? W2vT : WqkT;

  __shared__ __align__(16) u16 lA[2 * 128 * 32];
  __shared__ __align__(16) u16 lB[2 * 128 * 32];

  const int tid  = threadIdx.x;
  const int lane = tid & 63;
  const int wv   = tid >> 6;
  const int wm   = (wv >> 1) << 6;
  const int wn   = (wv & 1) << 6;
  const int l15  = lane & 15;
  const int rd_off = l15 * 64 + ((((lane >> 4) ^ (l15 >> 1)) & 3) << 4);

  f32x4_t acc[4][4];
#pragma unroll
  for (int i = 0; i < 4; ++i)
#pragma unroll
    for (int j = 0; j < 4; ++j)
      acc[i][j] = (f32x4_t){0.f, 0.f, 0.f, 0.f};

  const long ldA2 = (long)lda * 2, ldB2 = (long)ldb * 2;
  const int c_src = (tid & 3) ^ ((tid >> 3) & 3);
  const char* pA = (const char*)(A + (long)bm0 * lda) + (long)(tid >> 2) * ldA2 + (c_src << 4);
  const char* pB = (const char*)(B + (long)bn0 * ldb) + (long)(tid >> 2) * ldB2 + (c_src << 4);
  const int ldsbo = tid * 16;

  for (int k0 = 0; k0 < 1024; k0 += 64) {
    const long kb = (long)k0 * 2;
#pragma unroll
    for (int r = 0; r < 4; ++r) {
      const long go = (long)(r & 1) * 64 * ldA2 + (r >> 1) * 64;
      __builtin_amdgcn_global_load_lds(
          (const __attribute__((address_space(1))) unsigned int*)(pA + kb + go),
          (__attribute__((address_space(3))) unsigned int*)((char*)lA + ldsbo + r * 4096), 16, 0, 0);
    }
#pragma unroll
    for (int r = 0; r < 4; ++r) {
      const long go = (long)(r & 1) * 64 * ldB2 + (r >> 1) * 64;
      __builtin_amdgcn_global_load_lds(
          (const __attribute__((address_space(1))) unsigned int*)(pB + kb + go),
          (__attribute__((address_space(3))) unsigned int*)((char*)lB + ldsbo + r * 4096), 16, 0, 0);
    }
    __syncthreads();

    const char* lAb = (const char*)lA + wm * 64 + rd_off;
    const char* lBb = (const char*)lB + wn * 64 + rd_off;
#pragma unroll
    for (int s = 0; s < 2; ++s) {
      const int so = s * 8192;
      bf16x8_t b0 = *(const bf16x8_t*)(lBb + so + 0 * 1024);
      bf16x8_t b1 = *(const bf16x8_t*)(lBb + so + 1 * 1024);
      bf16x8_t b2 = *(const bf16x8_t*)(lBb + so + 2 * 1024);
      bf16x8_t b3 = *(const bf16x8_t*)(lBb + so + 3 * 1024);
#pragma unroll
      for (int mf = 0; mf < 4; ++mf) {
        bf16x8_t a = *(const bf16x8_t*)(lAb + so + mf * 1024);
        acc[mf][0] = __builtin_amdgcn_mfma_f32_16x16x32_bf16(a, b0, acc[mf][0], 0, 0, 0);
        acc[mf][1] = __builtin_amdgcn_mfma_f32_16x16x32_bf16(a, b1, acc[mf][1], 0, 0, 0);
        acc[mf][2] = __builtin_amdgcn_mfma_f32_16x16x32_bf16(a, b2, acc[mf][2], 0, 0, 0);
        acc[mf][3] = __builtin_amdgcn_mfma_f32_16x16x32_bf16(a, b3, acc[mf][3], 0, 0, 0);
      }
    }
    __syncthreads();
  }

  const int r4 = (lane >> 4) << 2;
#pragma unroll
  for (int mf = 0; mf < 4; ++mf)
#pragma unroll
    for (int nf = 0; nf < 4; ++nf) {
      const int col = bn0 + wn + nf * 16 + l15;
#pragma unroll
      for (int r = 0; r < 4; ++r)
        C[(long)(bm0 + wm + mf * 16 + r4 + r) * 1024 + col] = f2bf(acc[mf][nf][r]);
    }
}

// ---------------------------------------------------------------------------
// prep: blocks 0..8191 x->bf16; 8192..9215 wproj transpose (32x32 tiles);
//       9216..12287 w_qkv flat cast -> wfull bf16 [1024][3072]
__global__ __launch_bounds__(256)
void prep(const float* __restrict__ x, u16* __restrict__ xbf,
          const float* __restrict__ wqkv, u16* __restrict__ wfull,
          const float* __restrict__ wproj, u16* __restrict__ wprojT) {
  const int bid = blockIdx.x;
  if (bid < 8192) {
    const int i = bid * 256 + threadIdx.x;
    float4 v = ((const float4*)x)[i];
    u16x4 o = {f2bf(v.x), f2bf(v.y), f2bf(v.z), f2bf(v.w)};
    ((u16x4*)xbf)[i] = o;
    return;
  }
  if (bid < 9216) {
    const int tb = bid - 8192;           // 0..1023: wproj [1024][1024] transpose
    const int c0 = (tb & 31) * 32;
    const int r0 = (tb >> 5) * 32;
    __shared__ float t[32][33];
    const int tx = threadIdx.x & 31, ty = threadIdx.x >> 5;
#pragma unroll
    for (int i = 0; i < 32; i += 8)
      t[ty + i][tx] = wproj[(long)(r0 + ty + i) * 1024 + (c0 + tx)];
    __syncthreads();
#pragma unroll
    for (int i = 0; i < 32; i += 8)
      wprojT[(long)(c0 + ty + i) * 1024 + (r0 + tx)] = f2bf(t[tx][ty + i]);
    return;
  }
  const int i = (bid - 9216) * 256 + threadIdx.x;  // 3072 blocks x 1024 elems
  float4 v = ((const float4*)wqkv)[i];
  u16x4 o = {f2bf(v.x), f2bf(v.y), f2bf(v.z), f2bf(v.w)};
  ((u16x4*)wfull)[i] = o;
}

// ---------------------------------------------------------------------------
extern "C" void kernel_launch(void* const* d_in, const int* in_sizes, int n_in,
                              void* d_out, int out_size, void* d_ws, size_t ws_size,
                              hipStream_t stream) {
  (void)in_sizes; (void)n_in; (void)out_size; (void)ws_size;
  const float* x      = (const float*)d_in[0];
  const float* w_qkv  = (const float*)d_in[1];
  const float* w_proj = (const float*)d_in[2];
  const float* b_proj = (const float*)d_in[3];
  float* y = (float*)d_out;
  char*  ws = (char*)d_ws;

  // workspace layout
  u16* xbf    = (u16*)(ws);                  // 16 MB
  u16* t1     = (u16*)(ws + (16l << 20));    // 16 MB  [8192,1024] x@Wqk
  u16* WqkT   = (u16*)(ws + (32l << 20));    //  2 MB
  u16* W2vT   = (u16*)(ws + (34l << 20));    //  2 MB
  u16* wprojT = (u16*)(ws + (36l << 20));    //  2 MB
  u16* wfull  = (u16*)(ws + (38l << 20));    //  6 MB  [1024,3072] w_qkv bf16
  u16* VWT    = (u16*)(ws + (44l << 20));    // 16 MB  [4][1024][2048]
  u16* E      = (u16*)(ws + (60l << 20));    // 32 MB  [4][2048][2048]

  // 1) casts + wproj transpose
  prep<<<12288, 256, 0, stream>>>(x, xbf, w_qkv, wfull, w_proj, wprojT);
  // 2) WqkT + W2vT (one dispatch)
  gemm_w<<<dim3(8, 16), 256, 0, stream>>>(wfull, wprojT, WqkT, W2vT);
  // 3) [t1 | VW] = x @ [Wqk | W2v] : t1 row-major, VW transposed -> VWT
  gemm_bt<2, 0><<<dim3(16, 64, 1), 256, 0, stream>>>(
      xbf, WqkT, W2vT, t1, VWT, nullptr, 1024, 1024, 1024, 1024, 0, 0, 0);
  // 4) E = exp(t1 @ x^T / 32) causal; compact triangular grid
  gemm_bt<3, 1><<<dim3(136, 1, 4), 256, 0, stream>>>(
      t1, xbf, nullptr, E, nullptr, nullptr, 1024, 1024, 1024, 2048,
      (long)2048 * 1024, (long)2048 * 1024, (long)2048 * 2048);
  // 5) y = (E @ VW)/rowsum + bias : 64-row tiles, 1024 blocks = 4/CU
  pv64<<<dim3(8, 32, 4), 256, 0, stream>>>(E, VWT, y, b_proj);
}